// Round 10
// baseline (283.398 us; speedup 1.0000x reference)
//
#include <hip/hip_runtime.h>
#include <hip/hip_bf16.h>

typedef unsigned short u16;
typedef unsigned int u32;
typedef __attribute__((ext_vector_type(8))) short bf16x8;
typedef __attribute__((ext_vector_type(4))) float f32x4;

#define LOG2E 1.4426950408889634f

__device__ __forceinline__ float bf2f(u16 u){
  union { unsigned int i; float f; } v; v.i = ((unsigned int)u) << 16; return v.f;
}
__device__ __forceinline__ u16 f2bf(float f){
  union { float f; unsigned int i; } v; v.f = f;
  unsigned int i = v.i;
  return (u16)((i + 0x7fffu + ((i >> 16) & 1u)) >> 16);
}
// packed bf16 convert (v_cvt_pk_bf16_f32 on gfx950)
__device__ __forceinline__ u32 pk2(float a, float b){
  union { __hip_bfloat162 v; u32 u; } c;
  c.v = __float22bfloat162_rn(float2{a, b});
  return c.u;
}
__device__ __forceinline__ float ldin(const void* p, int i, int f){
  return f ? ((const float*)p)[i] : bf2f(((const u16*)p)[i]);
}
__device__ __forceinline__ bf16x8 pack8(const float* v){
  union { bf16x8 v8; u32 w[4]; } u;
  #pragma unroll
  for (int j = 0; j < 4; ++j) u.w[j] = pk2(v[2*j], v[2*j+1]);
  return u.v8;
}
__device__ __forceinline__ float fexp2(float x){
#if __has_builtin(__builtin_amdgcn_exp2f)
  return __builtin_amdgcn_exp2f(x);
#else
  return exp2f(x);
#endif
}

// ---------------------------------------------------------------------------
// Kernel S: sniff input dtype from msa_act's first 256 words.
// ---------------------------------------------------------------------------
__global__ void k_sniff(const unsigned int* __restrict__ msa_w, int* __restrict__ flag)
{
  int lane = threadIdx.x & 63;
  int lo0 = 0, expok = 0;
  #pragma unroll
  for (int j = 0; j < 4; ++j) {
    unsigned int w = msa_w[lane * 4 + j];
    if ((w & 0xffffu) == 0u) lo0++;
    unsigned int e = (w >> 7) & 0xffu;
    if (e >= 110u && e <= 140u) expok++;
  }
  #pragma unroll
  for (int off = 1; off < 64; off <<= 1) {
    lo0   += __shfl_xor(lo0,   off, 64);
    expok += __shfl_xor(expok, off, 64);
  }
  if (lane == 0 && blockIdx.x == 0)
    *flag = (lo0 > 200) ? 1 : ((expok > 200) ? 0 : 1);
}

// ---------------------------------------------------------------------------
// Kernel P: merged prep. blocks [0,80): weight transpose; [80,1104): pair
// LN + z (bf16, pre-scaled by log2e); [1104,9296): msa LN -> m_bf16.
// ---------------------------------------------------------------------------
__global__ __launch_bounds__(256) void k_prep(
    const void* __restrict__ wq, const void* __restrict__ wk,
    const void* __restrict__ wv, const void* __restrict__ wg,
    const void* __restrict__ wo,
    const void* __restrict__ pair, const void* __restrict__ png,
    const void* __restrict__ pnb, const void* __restrict__ w2d,
    const void* __restrict__ msa, const void* __restrict__ qng,
    const void* __restrict__ qnb, const int* __restrict__ flagp,
    u16* __restrict__ Wt, u16* __restrict__ wot,
    u16* __restrict__ z_bf, u16* __restrict__ m_bf)
{
  __shared__ u16 SMEM[64 * 136 + 16 * 136];
  const int flag = *flagp;
  const int t = threadIdx.x, lane = t & 63, wave = t >> 6;
  const int bid = blockIdx.x;

  if (bid < 80) {
    // ---- weight transpose, one 64x64 tile per block ----
    u16* T = SMEM;                       // 64*72
    const int mat = bid >> 4, tile = bid & 15;
    const int R0 = (tile >> 2) * 64, C0 = (tile & 3) * 64;
    const void* src = (mat == 0) ? wq : (mat == 1) ? wk : (mat == 2) ? wv
                    : (mat == 3) ? wg : wo;
    u16* dst = (mat < 4) ? (Wt + mat * 65536) : wot;
    {
      int i = t >> 2, j0 = (t & 3) * 16;
      #pragma unroll
      for (int e = 0; e < 8; ++e) {
        float a = ldin(src, (R0 + i) * 256 + C0 + j0 + 2*e,     flag);
        float b = ldin(src, (R0 + i) * 256 + C0 + j0 + 2*e + 1, flag);
        *(u32*)(T + i * 72 + j0 + 2*e) = pk2(a, b);
      }
    }
    __syncthreads();
    {
      int j = t >> 2, i0 = (t & 3) * 16;
      u16 o[16];
      #pragma unroll
      for (int e = 0; e < 16; ++e) o[e] = T[(i0 + e) * 72 + j];
      *(uint4*)(dst + (C0 + j) * 256 + R0 + i0)     = *(const uint4*)o;
      *(uint4*)(dst + (C0 + j) * 256 + R0 + i0 + 8) = *(const uint4*)(o + 8);
    }
  } else if (bid < 80 + 1024) {
    // ---- pair LayerNorm + z via MFMA; z stored *log2e ----
    u16* As = SMEM;                      // 64*136
    u16* Bs = SMEM + 64 * 136;           // 16*136
    const int g = lane >> 4, l15 = lane & 15;
    const int rowBase = (bid - 80) * 64;
    if (t < 128) {
      #pragma unroll
      for (int n = 0; n < 16; ++n)
        Bs[n * 136 + t] = (n < 8) ? f2bf(ldin(w2d, t * 8 + n, flag)) : (u16)0;
    }
    {
      int lrow = t >> 2, cb = (t & 3) * 32;
      int base = (rowBase + lrow) * 128 + cb;
      float x[32];
      if (flag) {
        const float* p = (const float*)pair + base;
        #pragma unroll
        for (int j = 0; j < 8; ++j) {
          float4 f4 = *(const float4*)(p + 4 * j);
          x[4*j] = f4.x; x[4*j+1] = f4.y; x[4*j+2] = f4.z; x[4*j+3] = f4.w;
        }
      } else {
        const u16* p = (const u16*)pair + base;
        #pragma unroll
        for (int j = 0; j < 4; ++j) {
          uint4 u = *(const uint4*)(p + 8 * j);
          const u16* hh = (const u16*)&u;
          #pragma unroll
          for (int e = 0; e < 8; ++e) x[8*j+e] = bf2f(hh[e]);
        }
      }
      float s = 0.f, sq = 0.f;
      #pragma unroll
      for (int j = 0; j < 32; ++j) { s += x[j]; sq += x[j] * x[j]; }
      s  += __shfl_xor(s, 1, 64);  s  += __shfl_xor(s, 2, 64);
      sq += __shfl_xor(sq, 1, 64); sq += __shfl_xor(sq, 2, 64);
      float mu = s * (1.f / 128.f);
      float var = sq * (1.f / 128.f) - mu * mu;
      float rs = rsqrtf(var + 1e-5f);
      float n_[32];
      #pragma unroll
      for (int j = 0; j < 32; ++j) {
        int c = cb + j;
        n_[j] = (x[j] - mu) * rs * ldin(png, c, flag) + ldin(pnb, c, flag);
      }
      u16* dst = As + lrow * 136 + cb;
      #pragma unroll
      for (int j = 0; j < 16; ++j)
        *(u32*)(dst + 2*j) = pk2(n_[2*j], n_[2*j+1]);
    }
    __syncthreads();
    f32x4 accz = {0.f, 0.f, 0.f, 0.f};
    #pragma unroll
    for (int kb = 0; kb < 4; ++kb) {
      bf16x8 a = *(const bf16x8*)(As + (wave * 16 + l15) * 136 + kb * 32 + g * 8);
      bf16x8 b = *(const bf16x8*)(Bs + l15 * 136 + kb * 32 + g * 8);
      accz = __builtin_amdgcn_mfma_f32_16x16x32_bf16(a, b, accz, 0, 0, 0);
    }
    if (l15 < 8) {
      #pragma unroll
      for (int r = 0; r < 4; ++r)
        z_bf[l15 * 65536 + rowBase + wave * 16 + g * 4 + r] = f2bf(accz[r] * LOG2E);
    }
  } else {
    // ---- msa LayerNorm -> m_bf16, one row per wave ----
    int row = (bid - 1104) * 4 + wave;
    float x[4];
    if (flag) {
      float4 f4 = *((const float4*)msa + row * 64 + lane);
      x[0]=f4.x; x[1]=f4.y; x[2]=f4.z; x[3]=f4.w;
    } else {
      uint2 u = *((const uint2*)msa + row * 64 + lane);
      const u16* hh = (const u16*)&u;
      #pragma unroll
      for (int j = 0; j < 4; ++j) x[j] = bf2f(hh[j]);
    }
    float s = 0.f, sq = 0.f;
    #pragma unroll
    for (int j = 0; j < 4; ++j) { s += x[j]; sq += x[j] * x[j]; }
    #pragma unroll
    for (int off = 1; off < 64; off <<= 1) {
      s  += __shfl_xor(s,  off, 64);
      sq += __shfl_xor(sq, off, 64);
    }
    float mu = s * (1.f / 256.f);
    float var = sq * (1.f / 256.f) - mu * mu;
    float rs = rsqrtf(var + 1e-5f);
    float y[4];
    #pragma unroll
    for (int j = 0; j < 4; ++j) {
      int c = lane * 4 + j;
      y[j] = (x[j] - mu) * rs * ldin(qng, c, flag) + ldin(qnb, c, flag);
    }
    uint2 o2;
    o2.x = pk2(y[0], y[1]);
    o2.y = pk2(y[2], y[3]);
    *((uint2*)m_bf + row * 64 + lane) = o2;
  }
}

// ---------------------------------------------------------------------------
// Kernel F: fused projections + attention, one block per (s,h).
// Round-10: round-8-proven per-kc S transpose (16x36 f32 buffer, in-bounds)
// fused with exp2+pack+PV; 3 blocks/CU (LDS 43.5 KB); Ks XOR-swizzled;
// q/g packed bf16 registers; log2e folded at producers.
// ---------------------------------------------------------------------------
__global__ __launch_bounds__(256, 3) void k_fused(
    const u16* __restrict__ m_bf, const u16* __restrict__ Wt,
    const void* __restrict__ bg, const u16* __restrict__ z_bf,
    const void* __restrict__ mask, const int* __restrict__ flagp,
    u16* __restrict__ og_ws)
{
  __shared__ u16 Ks[256 * 32];          // [k][chunk-swizzled d], 16 KB
  __shared__ u16 Vts[32 * 264];         // [d][k] pad, 16.9 KB
  __shared__ float Sb[4][16 * 36];      // per-wave transpose buffer, 9.2 KB
  __shared__ float Mb[256];             // mask bias * log2e
  const int flag = *flagp;
  const int t = threadIdx.x, lane = t & 63, wave = t >> 6;
  const int s_ = blockIdx.x, h = blockIdx.y;
  const int g = lane >> 4, l15 = lane & 15;

  Mb[t] = (1e9f * LOG2E) * (ldin(mask, s_ * 256 + t, flag) - 1.0f);

  const float qscale = 0.17677669529663687f * LOG2E;  // 1/sqrt(32) * log2e
  u32 qpk[4][2][2];   // per-tile packed bf16 q (C-layout)
  u32 gpk[4][2][2];   // per-tile packed bf16 sigmoid gates
  f32x4 zero = {0.f, 0.f, 0.f, 0.f};

  // ---- projections, two 32-row chunks (af = 64 VGPR each) ----
  #pragma unroll
  for (int c = 0; c < 2; ++c) {
    bf16x8 af[8][2];
    #pragma unroll
    for (int kb = 0; kb < 8; ++kb)
      #pragma unroll
      for (int mt = 0; mt < 2; ++mt)
        af[kb][mt] = *(const bf16x8*)(
            m_bf + (s_*256 + wave*64 + c*32 + mt*16 + l15)*256 + kb*32 + g*8);

    #pragma unroll
    for (int matid = 0; matid < 4; ++matid) {
      const u16* W = Wt + matid * 65536 + (h * 32) * 256;
      f32x4 acc[2][2];
      acc[0][0] = zero; acc[0][1] = zero; acc[1][0] = zero; acc[1][1] = zero;
      #pragma unroll
      for (int kb = 0; kb < 8; ++kb) {
        bf16x8 b0 = *(const bf16x8*)(W + l15 * 256        + kb * 32 + g * 8);
        bf16x8 b1 = *(const bf16x8*)(W + (16 + l15) * 256 + kb * 32 + g * 8);
        #pragma unroll
        for (int mt = 0; mt < 2; ++mt) {
          acc[mt][0] = __builtin_amdgcn_mfma_f32_16x16x32_bf16(af[kb][mt], b0, acc[mt][0], 0, 0, 0);
          acc[mt][1] = __builtin_amdgcn_mfma_f32_16x16x32_bf16(af[kb][mt], b1, acc[mt][1], 0, 0, 0);
        }
      }
      #pragma unroll
      for (int mt = 0; mt < 2; ++mt) {
        const int tile = c * 2 + mt;
        if (matid == 0) {
          #pragma unroll
          for (int nt = 0; nt < 2; ++nt) {
            qpk[tile][nt][0] = pk2(acc[mt][nt][0] * qscale, acc[mt][nt][1] * qscale);
            qpk[tile][nt][1] = pk2(acc[mt][nt][2] * qscale, acc[mt][nt][3] * qscale);
          }
        } else if (matid == 3) {
          #pragma unroll
          for (int nt = 0; nt < 2; ++nt) {
            float b = ldin(bg, h * 32 + nt * 16 + l15, flag);
            float s0 = 1.f / (1.f + __expf(-(acc[mt][nt][0] + b)));
            float s1 = 1.f / (1.f + __expf(-(acc[mt][nt][1] + b)));
            float s2 = 1.f / (1.f + __expf(-(acc[mt][nt][2] + b)));
            float s3 = 1.f / (1.f + __expf(-(acc[mt][nt][3] + b)));
            gpk[tile][nt][0] = pk2(s0, s1);
            gpk[tile][nt][1] = pk2(s2, s3);
          }
        } else {
          #pragma unroll
          for (int nt = 0; nt < 2; ++nt)
            #pragma unroll
            for (int r = 0; r < 4; ++r) {
              int rowl = wave * 64 + c * 32 + mt * 16 + g * 4 + r;
              int dd = nt * 16 + l15;
              u16 o = f2bf(acc[mt][nt][r]);
              if (matid == 1)   // K, swizzle: chunk' = chunk ^ (k&3); k&3 == r
                Ks[rowl * 32 + (((dd >> 3) ^ (r & 3)) << 3) + (dd & 7)] = o;
              else              // V transposed
                Vts[dd * 264 + rowl] = o;
            }
        }
      }
    }
  }
  __syncthreads();

  // ---- attention on the wave's 64 q rows ----
  float* Sw = &Sb[wave][0];
  u16* Swu = (u16*)Sw;                  // [16][72] u16 view
  const u16* zb_base = z_bf + h * 65536;

  for (int qt = 0; qt < 4; ++qt) {
    const int qbase = wave * 64 + qt * 16;
    // q: packed regs -> Swu -> A-layout fragment
    asm volatile("s_waitcnt lgkmcnt(0)" ::: "memory");
    #pragma unroll
    for (int nt = 0; nt < 2; ++nt)
      #pragma unroll
      for (int r = 0; r < 4; ++r)
        Swu[(g * 4 + r) * 72 + nt * 16 + l15] =
            (u16)(qpk[qt][nt][r >> 1] >> ((r & 1) * 16));
    asm volatile("s_waitcnt lgkmcnt(0)" ::: "memory");
    bf16x8 aq = *(const bf16x8*)(Swu + l15 * 72 + g * 8);

    f32x4 S[16];
    #pragma unroll
    for (int kt = 0; kt < 16; ++kt) {
      bf16x8 bk = *(const bf16x8*)(Ks + (kt * 16 + l15) * 32 + ((g ^ (l15 & 3)) << 3));
      S[kt] = __builtin_amdgcn_mfma_f32_16x16x32_bf16(aq, bk, zero, 0, 0, 0);
    }
    // z prefetch (scattered 16B, L2-resident 1 MB)
    const u16* zb = zb_base + (qbase + l15) * 256;
    uint4 zu[8];
    #pragma unroll
    for (int kc = 0; kc < 8; ++kc) zu[kc] = *(const uint4*)(zb + kc * 32 + g * 8);

    float sm = 0.f;
    f32x4 O0 = zero, O1 = zero;
    #pragma unroll
    for (int kc = 0; kc < 8; ++kc) {
      asm volatile("s_waitcnt lgkmcnt(0)" ::: "memory");
      #pragma unroll
      for (int half = 0; half < 2; ++half)
        #pragma unroll
        for (int r = 0; r < 4; ++r)
          Sw[(g * 4 + r) * 36 + half * 16 + l15] = S[kc * 2 + half][r];
      asm volatile("s_waitcnt lgkmcnt(0)" ::: "memory");
      float4 t0 = *(const float4*)(Sw + l15 * 36 + g * 8);
      float4 t1 = *(const float4*)(Sw + l15 * 36 + g * 8 + 4);
      float4 m0 = *(const float4*)(Mb + kc * 32 + g * 8);
      float4 m1 = *(const float4*)(Mb + kc * 32 + g * 8 + 4);
      const u16* zh = (const u16*)&zu[kc];
      float L[8];
      L[0] = fexp2(t0.x + m0.x + bf2f(zh[0]));
      L[1] = fexp2(t0.y + m0.y + bf2f(zh[1]));
      L[2] = fexp2(t0.z + m0.z + bf2f(zh[2]));
      L[3] = fexp2(t0.w + m0.w + bf2f(zh[3]));
      L[4] = fexp2(t1.x + m1.x + bf2f(zh[4]));
      L[5] = fexp2(t1.y + m1.y + bf2f(zh[5]));
      L[6] = fexp2(t1.z + m1.z + bf2f(zh[6]));
      L[7] = fexp2(t1.w + m1.w + bf2f(zh[7]));
      sm += ((L[0] + L[1]) + (L[2] + L[3])) + ((L[4] + L[5]) + (L[6] + L[7]));
      bf16x8 ap  = pack8(L);
      bf16x8 bv0 = *(const bf16x8*)(Vts + l15 * 264 + kc * 32 + g * 8);
      bf16x8 bv1 = *(const bf16x8*)(Vts + (16 + l15) * 264 + kc * 32 + g * 8);
      O0 = __builtin_amdgcn_mfma_f32_16x16x32_bf16(ap, bv0, O0, 0, 0, 0);
      O1 = __builtin_amdgcn_mfma_f32_16x16x32_bf16(ap, bv1, O1, 0, 0, 0);
    }
    sm += __shfl_xor(sm, 16, 64);
    sm += __shfl_xor(sm, 32, 64);
    #pragma unroll
    for (int r = 0; r < 4; ++r) {
      float smr = __shfl(sm, g * 4 + r, 64);
      float inv = 1.0f / smr;
      int qq = qbase + g * 4 + r;
      int base = (s_ * 256 + qq) * 256 + h * 32;
      float g0 = bf2f((u16)(gpk[qt][0][r >> 1] >> ((r & 1) * 16)));
      float g1 = bf2f((u16)(gpk[qt][1][r >> 1] >> ((r & 1) * 16)));
      og_ws[base + l15]      = f2bf(O0[r] * inv * g0);
      og_ws[base + 16 + l15] = f2bf(O1[r] * inv * g1);
    }
  }
}

// ---------------------------------------------------------------------------
// Kernel O: output projection GEMM, zero-LDS register-resident A, grid
// (256,2) for 2 blocks/CU. M=32768, N=256, K=256. +bo.
// ---------------------------------------------------------------------------
__global__ __launch_bounds__(256, 2) void k_outproj(
    const u16* __restrict__ og, const u16* __restrict__ wot,
    const void* __restrict__ bo, const int* __restrict__ flagp,
    void* __restrict__ outv)
{
  const int flag = *flagp;
  const int t = threadIdx.x, lane = t & 63, wave = t >> 6;
  const int wm = (wave >> 1) * 64, wn = (wave & 1) * 64;
  const int rowBase = blockIdx.x * 128;
  const int ct = blockIdx.y;
  const int g = lane >> 4, l15 = lane & 15;

  bf16x8 af[8][4];
  #pragma unroll
  for (int kb = 0; kb < 8; ++kb)
    #pragma unroll
    for (int mt = 0; mt < 4; ++mt)
      af[kb][mt] = *(const bf16x8*)(
          og + (rowBase + wm + mt * 16 + l15) * 256 + kb * 32 + g * 8);

  const u16* Wb = wot + (ct * 128 + wn) * 256;
  f32x4 acc[4][4];
  f32x4 zero = {0.f, 0.f, 0.f, 0.f};
  #pragma unroll
  for (int i = 0; i < 4; ++i)
    #pragma unroll
    for (int j = 0; j < 4; ++j) acc[i][j] = zero;
  #pragma unroll
  for (int kb = 0; kb < 8; ++kb) {
    bf16x8 bb[4];
    #pragma unroll
    for (int nt = 0; nt < 4; ++nt)
      bb[nt] = *(const bf16x8*)(Wb + (nt * 16 + l15) * 256 + kb * 32 + g * 8);
    #pragma unroll
    for (int mt = 0; mt < 4; ++mt)
      #pragma unroll
      for (int nt = 0; nt < 4; ++nt)
        acc[mt][nt] = __builtin_amdgcn_mfma_f32_16x16x32_bf16(
            af[kb][mt], bb[nt], acc[mt][nt], 0, 0, 0);
  }
  #pragma unroll
  for (int mt = 0; mt < 4; ++mt)
    #pragma unroll
    for (int nt = 0; nt < 4; ++nt)
      #pragma unroll
      for (int r = 0; r < 4; ++r) {
        int row = rowBase + wm + mt * 16 + g * 4 + r;
        int col = ct * 128 + wn + nt * 16 + l15;
        float val = acc[mt][nt][r] + ldin(bo, col, flag);
        if (flag) ((float*)outv)[row * 256 + col] = val;
        else      ((u16*)outv)[row * 256 + col]   = f2bf(val);
      }
}

// ---------------------------------------------------------------------------
extern "C" void kernel_launch(void* const* d_in, const int* in_sizes, int n_in,
                              void* d_out, int out_size, void* d_ws, size_t ws_size,
                              hipStream_t stream)
{
  const void* msa  = d_in[0];
  const void* pair = d_in[1];
  const void* mask = d_in[2];
  const void* qng  = d_in[3];
  const void* qnb  = d_in[4];
  const void* png  = d_in[5];
  const void* pnb  = d_in[6];
  const void* w2d  = d_in[7];
  const void* wq   = d_in[8];
  const void* wk   = d_in[9];
  const void* wv   = d_in[10];
  const void* wg   = d_in[11];
  const void* bg   = d_in[12];
  const void* wo   = d_in[13];
  const void* bo   = d_in[14];

  char* ws = (char*)d_ws;
  u16* z_bf  = (u16*)(ws + 0);                  //  1,048,576
  u16* Wt    = (u16*)(ws + 1048576);            //    524,288
  u16* wot   = (u16*)(ws + 1572864);            //    131,072
  int* flag  = (int*)(ws + 1703936);            //        256
  u16* m_bf  = (u16*)(ws + 1704192);            // 16,777,216
  u16* og_ws = (u16*)(ws + 18481408);           // 16,777,216 -> ends 35,258,624

  hipLaunchKernelGGL(k_sniff, dim3(1), dim3(64), 0, stream,
                     (const unsigned int*)msa, flag);
  hipLaunchKernelGGL(k_prep, dim3(9296), dim3(256), 0, stream,
                     wq, wk, wv, wg, wo, pair, png, pnb, w2d,
                     msa, qng, qnb, flag, Wt, wot, z_bf, m_bf);
  hipLaunchKernelGGL(k_fused, dim3(128, 8), dim3(256), 0, stream,
                     m_bf, Wt, bg, z_bf, mask, flag, og_ws);
  hipLaunchKernelGGL(k_outproj, dim3(256, 2), dim3(256), 0, stream,
                     og_ws, wot, bo, flag, d_out);
}